// Round 9
// baseline (277.344 us; speedup 1.0000x reference)
//
#include <hip/hip_runtime.h>
#include <math.h>

#define B_ 64
#define I_ 4096
#define P_ 8      // Din
#define N_ 10
#define D_ 16
#define ND_ 160   // N*D
#define BND_ (B_*ND_)   // 10240
#define EPS_ 1e-7f

#define IPB_ 8                 // i per block
#define ROWS_ (I_ / IPB_)      // 512 blocks
#define WTILE_ (N_ * P_ * D_)  // 1280 floats of W per i
#define LGS_ 11                // padded logit row stride (odd -> bank-clean)

// Transpose x [B,I,P] -> xT [I,B,P] so the pass kernel's per-(i,wave) x read
// is a contiguous 2 KB coalesced segment (lane b reads 32 B at stride 32 B).
__global__ __launch_bounds__(256)
void xT_kernel(const float* __restrict__ x, float* __restrict__ xT)
{
    int idx = blockIdx.x * 256 + threadIdx.x;     // 64*4096*8 = 2,097,152
    int p = idx & 7;
    int i = (idx >> 3) & (I_ - 1);
    int b = idx >> 15;
    xT[((size_t)i * B_ + b) * P_ + p] = x[idx];   // read coalesced, write 32B chunks
}

// Round-9 structure: R7/R8 dataflow with SCALAR (SMEM) W delivery.
//  - lane = b (64 batch), block = 320 thr = 5 waves, wave w owns n-pair {2w,2w+1}.
//  - KEY FIX vs R7: n0 passes through __builtin_amdgcn_readfirstlane, which
//    divergence analysis treats as always-uniform -> the whole W address chain
//    (blockIdx + il + n0u + compile-time offsets) is uniform -> the compiler
//    selects s_load (SMEM). One s_load_dwordx16 feeds 64 lanes; v_fmac v,s,v
//    reads the SGPR for free. R7 without this had SGPR_Count=32 (vector loads,
//    latency-bound at 12% VALU); R8's LDS broadcast cost a DS issue slot per
//    16B (64 ds_read_b128/wave-il ~= the VALU time -> 50/50 plateau).
//  - u_hat pair tv[2][16] in regs, single sweep; logit dot in-thread (zero
//    cross-lane reductions — R2/R4/R6 proved shuffle/DPP trees are the wall).
//  - softmax exchange: 2 floats/thread via double-buffered lgsh (5.6 KB), one
//    barrier per il.
// __launch_bounds__(320) only — NO min-waves arg (round 3: forcing occupancy
// caused 350 MB/pass scratch spill). DO NOT tighten.
template<int MODE, int IPB>
__global__ __launch_bounds__(320)
void digitcaps_pass(const float* __restrict__ xT, const float* __restrict__ W,
                    const float* __restrict__ Vc, float* __restrict__ part)
{
    __shared__ float lgsh[2][B_][LGS_];
    const int t = threadIdx.x;
    const int b = t & 63;
    // per-wave uniform n-pair base, FORCED into an SGPR for uniformity analysis
    const int n0 = __builtin_amdgcn_readfirstlane((t >> 6) * 2);
    const int i0 = blockIdx.x * IPB;

    float vc[2][D_];
    if (MODE == 1) {
#pragma unroll
        for (int q = 0; q < 2; ++q) {
            const float4* vp = (const float4*)(Vc + (size_t)b * ND_ + (n0 + q) * D_);
#pragma unroll
            for (int d4 = 0; d4 < 4; ++d4) {
                float4 vv = vp[d4];
                vc[q][d4 * 4 + 0] = vv.x; vc[q][d4 * 4 + 1] = vv.y;
                vc[q][d4 * 4 + 2] = vv.z; vc[q][d4 * 4 + 3] = vv.w;
            }
        }
    }

    float acc[2][D_];
#pragma unroll
    for (int q = 0; q < 2; ++q)
#pragma unroll
        for (int d = 0; d < D_; ++d) acc[q][d] = 0.f;

    // preload x for il=0
    float xv[P_];
    {
        const float4* xp = (const float4*)(xT + ((size_t)i0 * B_ + b) * P_);
        float4 a0 = xp[0], a1 = xp[1];
        xv[0]=a0.x; xv[1]=a0.y; xv[2]=a0.z; xv[3]=a0.w;
        xv[4]=a1.x; xv[5]=a1.y; xv[6]=a1.z; xv[7]=a1.w;
    }

#pragma unroll 1
    for (int il = 0; il < IPB; ++il) {
        const int i = i0 + il;
        // fully uniform W slice base for this wave's n-pair: -> s_load
        const float* __restrict__ Wt = W + (size_t)i * WTILE_ + n0 * (P_ * D_);

        float tv[2][D_];
#pragma unroll
        for (int q = 0; q < 2; ++q) {
            const float* __restrict__ Wq = Wt + q * (P_ * D_);
#pragma unroll
            for (int d = 0; d < D_; ++d) tv[q][d] = 0.f;
#pragma unroll
            for (int p = 0; p < P_; ++p)
#pragma unroll
                for (int d = 0; d < D_; ++d)   // Wq[] uniform -> SGPR operand
                    tv[q][d] = fmaf(Wq[p * D_ + d], xv[p], tv[q][d]);
        }

        // prefetch x for il+1 early (hide VMEM latency under softmax/acc VALU)
        float xn[P_];
        if (il + 1 < IPB) {
            const float4* xp = (const float4*)(xT + ((size_t)(i0 + il + 1) * B_ + b) * P_);
            float4 a0 = xp[0], a1 = xp[1];
            xn[0]=a0.x; xn[1]=a0.y; xn[2]=a0.z; xn[3]=a0.w;
            xn[4]=a1.x; xn[5]=a1.y; xn[6]=a1.z; xn[7]=a1.w;
        }

        if (MODE == 0) {
            // uniform c (softmax of zeros) -> 0.1 scale applied in reduce
#pragma unroll
            for (int q = 0; q < 2; ++q)
#pragma unroll
                for (int d = 0; d < D_; ++d) acc[q][d] += tv[q][d];
        } else {
            float lgq[2];
#pragma unroll
            for (int q = 0; q < 2; ++q) {
                float lA = 0.f, lB = 0.f;
#pragma unroll
                for (int d = 0; d < 8; ++d) {
                    lA = fmaf(tv[q][d], vc[q][d], lA);
                    lB = fmaf(tv[q][d + 8], vc[q][d + 8], lB);
                }
                lgq[q] = lA + lB;
            }
            const int buf = il & 1;
            lgsh[buf][b][n0]     = lgq[0];
            lgsh[buf][b][n0 + 1] = lgq[1];
            __syncthreads();
            float lg[N_];
#pragma unroll
            for (int n = 0; n < N_; ++n) lg[n] = lgsh[buf][b][n];
            float m = lg[0];
#pragma unroll
            for (int n = 1; n < N_; ++n) m = fmaxf(m, lg[n]);
            float se = 0.f;
#pragma unroll
            for (int n = 0; n < N_; ++n) se += __expf(lg[n] - m);
            float inv = 1.f / se;
            float cq0 = __expf(lgq[0] - m) * inv;
            float cq1 = __expf(lgq[1] - m) * inv;
#pragma unroll
            for (int d = 0; d < D_; ++d) {
                acc[0][d] = fmaf(cq0, tv[0][d], acc[0][d]);
                acc[1][d] = fmaf(cq1, tv[1][d], acc[1][d]);
            }
        }

#pragma unroll
        for (int p = 0; p < P_; ++p) xv[p] = xn[p];
    }

    // store partials transposed [blk][nd][b]: lane b contiguous -> coalesced
    float* __restrict__ po = part + (size_t)blockIdx.x * BND_;
#pragma unroll
    for (int q = 0; q < 2; ++q)
#pragma unroll
        for (int d = 0; d < D_; ++d)
            po[((n0 + q) * D_ + d) * B_ + b] = acc[q][d];
}

// Parallel-wide reduce over part rows (layout [row][nd*64+b]). Block handles
// 16 k-values; 16 threads per k sum rows/16 partials with coalesced loads.
__global__ __launch_bounds__(256)
void digitcaps_reduce(const float* __restrict__ part, int rows,
                      float scale, int mode,
                      float* __restrict__ Vc, float* __restrict__ out)
{
    __shared__ float sm[4][16];
    const int t = threadIdx.x;
    const int kk = t & 15;
    const int tp = t >> 4;                // 0..15
    const int k = blockIdx.x * 16 + kk;

    float s = 0.f;
    const int steps = rows >> 4;
    const float* __restrict__ p0 = part + (size_t)tp * BND_ + k;
    const size_t stride = (size_t)16 * BND_;
#pragma unroll 8
    for (int j = 0; j < steps; ++j)
        s += p0[(size_t)j * stride];

    s += __shfl_down(s, 32);
    s += __shfl_down(s, 16);
    if ((t & 63) < 16) sm[t >> 6][kk] = s;
    __syncthreads();

    if (t < 16) {
        float tot = (sm[0][t] + sm[1][t]) + (sm[2][t] + sm[3][t]);
        tot *= scale;
        float sq = tot * tot;
        float v = tot * (sq / ((1.f + sq) * sqrtf(sq + EPS_)));
        int k2 = blockIdx.x * 16 + t;          // k2 = nd*64 + b (partial layout)
        int j = (k2 & 63) * ND_ + (k2 >> 6);   // natural [b][n][d] layout
        if (mode == 0)      Vc[j] = v;         // after iter 0: Vc = v0
        else if (mode == 1) Vc[j] += v;        // after iter 1: Vc = v0 + v1
        else                out[j] = v;        // final output [B,N,1,D]
    }
}

extern "C" void kernel_launch(void* const* d_in, const int* in_sizes, int n_in,
                              void* d_out, int out_size, void* d_ws, size_t ws_size,
                              hipStream_t stream)
{
    const float* x = (const float*)d_in[0];   // [64, 4096, 8] f32
    const float* W = (const float*)d_in[1];   // [4096, 10, 8, 16] f32
    float* out = (float*)d_out;               // [64, 10, 1, 16] f32

    // ws layout: part (512*10240 f) | Vc (10240 f) | xT (2,097,152 f) = 29.4 MB
    // (measured ws ~268 MB from the harness fill kernels — plenty)
    float* part = (float*)d_ws;
    float* Vc   = part + (size_t)ROWS_ * BND_;
    float* xT   = Vc + BND_;

    dim3 pblk(320), pgrid(ROWS_), rblk(256), rgrid(BND_ / 16);

    xT_kernel<<<dim3((B_ * I_ * P_) / 256), dim3(256), 0, stream>>>(x, xT);

    for (int pass = 0; pass < 3; ++pass) {
        if (pass == 0)
            digitcaps_pass<0, IPB_><<<pgrid, pblk, 0, stream>>>(xT, W, nullptr, part);
        else
            digitcaps_pass<1, IPB_><<<pgrid, pblk, 0, stream>>>(xT, W, Vc, part);
        digitcaps_reduce<<<rgrid, rblk, 0, stream>>>(part, ROWS_,
                                                     pass == 0 ? 0.1f : 1.0f, pass, Vc, out);
    }
}

// Round 10
// 182.233 us; speedup vs baseline: 1.5219x; 1.5219x over previous
//
#include <hip/hip_runtime.h>
#include <math.h>

#define B_ 64
#define I_ 4096
#define P_ 8      // Din
#define N_ 10
#define D_ 16
#define ND_ 160   // N*D
#define BND_ (B_*ND_)   // 10240
#define EPS_ 1e-7f

#define IPB_ 8                 // i per block
#define ROWS_ (I_ / IPB_)      // 512 blocks
#define WTILE_ (N_ * P_ * D_)  // 1280 floats of W per i
#define LGS_ 11                // padded logit row stride (odd -> bank-clean)

// Transpose x [B,I,P] -> xT [I,B,P] so the pass kernel's per-(i,b) x read is a
// contiguous 32 B chunk, coalesced across consecutive-b lanes.
__global__ __launch_bounds__(256)
void xT_kernel(const float* __restrict__ x, float* __restrict__ xT)
{
    int idx = blockIdx.x * 256 + threadIdx.x;     // 64*4096*8 = 2,097,152
    int p = idx & 7;
    int i = (idx >> 3) & (I_ - 1);
    int b = idx >> 15;
    xT[((size_t)i * B_ + b) * P_ + p] = x[idx];
}

// Round-10: R8's LDS W staging + 2-b-per-thread lane map.
//  - Delivery ledger (measured): global-vector W (R5/R7) = latency wall @ 8-12%
//    VALU; SMEM W (R9) = SGPR capacity forces serialized lgkmcnt waits, 72 us;
//    16-lane shuffle/DPP logit trees (R2/R4/R6) = DS/hazard wall; R8 LDS
//    broadcast = best, but 64 ds_read_b128/wave-il x 1 KB/read = LDS-BW-bound.
//  - Fix: lane = (q = lane>>5, bl = lane&31); wave w covers n-pair {2w,2w+1}
//    x 64 b. Thread owns ONE n (n = 2w+q) and TWO b (bl, bl+32): its 32
//    ds_read_b128 per il feed 512 FMAs (2x R8's ratio) -> VALU-dominated.
//    Half-wave read addresses differ by 512 B = same banks, 2-way broadcast
//    = free (m136).
//  - Logit dot in-thread (owns all d); softmax exchange via 5.6 KB dbuf lgsh,
//    one barrier per il (dbuf => write(il+1) can't race read(il)).
// __launch_bounds__(320) only — NO min-waves arg (R3: forcing occupancy caused
// 350 MB/pass scratch spill). DO NOT tighten.
template<int MODE>
__global__ __launch_bounds__(320)
void digitcaps_pass(const float* __restrict__ xT, const float* __restrict__ W,
                    const float* __restrict__ Vc, float* __restrict__ part)
{
    __shared__ float wsh[IPB_ * WTILE_];                   // 40960 B
    __shared__ float lgsh[(MODE == 1) ? 2 : 1][B_][LGS_];  // 5632 B when used
    const int t = threadIdx.x;
    const int lane = t & 63;
    const int wv = t >> 6;          // 0..4
    const int q  = lane >> 5;       // which n of the wave's pair
    const int bl = lane & 31;       // owns b = bl and bl+32
    const int n  = 2 * wv + q;
    const int i0 = blockIdx.x * IPB_;

    // ---- stage W[i0..i0+8) into LDS: 10240 floats = 2560 float4, 8/thread ----
    {
        const float4* __restrict__ Wg = (const float4*)(W + (size_t)i0 * WTILE_);
        float4* __restrict__ Ws = (float4*)wsh;
#pragma unroll
        for (int c = 0; c < (IPB_ * WTILE_) / 4 / 320; ++c)
            Ws[c * 320 + t] = Wg[c * 320 + t];             // coalesced
    }

    float vc[2][D_];
    if (MODE == 1) {
#pragma unroll
        for (int h = 0; h < 2; ++h) {
            const float4* vp = (const float4*)(Vc + (size_t)(bl + 32 * h) * ND_ + n * D_);
#pragma unroll
            for (int d4 = 0; d4 < 4; ++d4) {
                float4 vv = vp[d4];
                vc[h][d4 * 4 + 0] = vv.x; vc[h][d4 * 4 + 1] = vv.y;
                vc[h][d4 * 4 + 2] = vv.z; vc[h][d4 * 4 + 3] = vv.w;
            }
        }
    }

    float acc[2][D_];
#pragma unroll
    for (int h = 0; h < 2; ++h)
#pragma unroll
        for (int d = 0; d < D_; ++d) acc[h][d] = 0.f;

    // preload x (il=0) for both b's
    float xv[2][P_];
#pragma unroll
    for (int h = 0; h < 2; ++h) {
        const float4* xp = (const float4*)(xT + ((size_t)i0 * B_ + bl + 32 * h) * P_);
        float4 a0 = xp[0], a1 = xp[1];
        xv[h][0]=a0.x; xv[h][1]=a0.y; xv[h][2]=a0.z; xv[h][3]=a0.w;
        xv[h][4]=a1.x; xv[h][5]=a1.y; xv[h][6]=a1.z; xv[h][7]=a1.w;
    }

    __syncthreads();   // wsh staged (also drains x preload)

#pragma unroll 1
    for (int il = 0; il < IPB_; ++il) {
        // u_hat for (n, b=bl) and (n, b=bl+32): 32 ds_read_b128, 512 FMA
        const float* __restrict__ Wn = wsh + il * WTILE_ + n * (P_ * D_);
        float tv[2][D_];
#pragma unroll
        for (int h = 0; h < 2; ++h)
#pragma unroll
            for (int d = 0; d < D_; ++d) tv[h][d] = 0.f;
#pragma unroll
        for (int p = 0; p < P_; ++p) {
            const float4* __restrict__ wp = (const float4*)(Wn + p * D_);
            float x0 = xv[0][p], x1 = xv[1][p];
#pragma unroll
            for (int d4 = 0; d4 < 4; ++d4) {
                float4 wvv = wp[d4];                       // ds_read_b128, 2-way bcast
                tv[0][d4*4+0] = fmaf(wvv.x, x0, tv[0][d4*4+0]);
                tv[0][d4*4+1] = fmaf(wvv.y, x0, tv[0][d4*4+1]);
                tv[0][d4*4+2] = fmaf(wvv.z, x0, tv[0][d4*4+2]);
                tv[0][d4*4+3] = fmaf(wvv.w, x0, tv[0][d4*4+3]);
                tv[1][d4*4+0] = fmaf(wvv.x, x1, tv[1][d4*4+0]);
                tv[1][d4*4+1] = fmaf(wvv.y, x1, tv[1][d4*4+1]);
                tv[1][d4*4+2] = fmaf(wvv.z, x1, tv[1][d4*4+2]);
                tv[1][d4*4+3] = fmaf(wvv.w, x1, tv[1][d4*4+3]);
            }
        }

        // prefetch x for il+1 (hide VMEM latency under softmax/acc VALU)
        float xn[2][P_];
        if (il + 1 < IPB_) {
#pragma unroll
            for (int h = 0; h < 2; ++h) {
                const float4* xp = (const float4*)(xT + ((size_t)(i0 + il + 1) * B_ + bl + 32 * h) * P_);
                float4 a0 = xp[0], a1 = xp[1];
                xn[h][0]=a0.x; xn[h][1]=a0.y; xn[h][2]=a0.z; xn[h][3]=a0.w;
                xn[h][4]=a1.x; xn[h][5]=a1.y; xn[h][6]=a1.z; xn[h][7]=a1.w;
            }
        }

        if (MODE == 0) {
            // uniform c (softmax of zeros) -> 0.1 scale applied in reduce
#pragma unroll
            for (int h = 0; h < 2; ++h)
#pragma unroll
                for (int d = 0; d < D_; ++d) acc[h][d] += tv[h][d];
        } else {
            // logit for (n, both b) — full d-dot in-thread, no cross-lane
            float lgq[2];
#pragma unroll
            for (int h = 0; h < 2; ++h) {
                float lA = 0.f, lB = 0.f;
#pragma unroll
                for (int d = 0; d < 8; ++d) {
                    lA = fmaf(tv[h][d], vc[h][d], lA);
                    lB = fmaf(tv[h][d + 8], vc[h][d + 8], lB);
                }
                lgq[h] = lA + lB;
            }
            const int buf = il & 1;
            lgsh[buf][bl][n]      = lgq[0];
            lgsh[buf][bl + 32][n] = lgq[1];
            __syncthreads();
            float cq[2];
#pragma unroll
            for (int h = 0; h < 2; ++h) {
                float lg[N_];
#pragma unroll
                for (int nn = 0; nn < N_; ++nn) lg[nn] = lgsh[buf][bl + 32 * h][nn];
                float m = lg[0];
#pragma unroll
                for (int nn = 1; nn < N_; ++nn) m = fmaxf(m, lg[nn]);
                float se = 0.f;
#pragma unroll
                for (int nn = 0; nn < N_; ++nn) se += __expf(lg[nn] - m);
                cq[h] = __expf(lgq[h] - m) / se;
            }
#pragma unroll
            for (int d = 0; d < D_; ++d) {
                acc[0][d] = fmaf(cq[0], tv[0][d], acc[0][d]);
                acc[1][d] = fmaf(cq[1], tv[1][d], acc[1][d]);
            }
        }

#pragma unroll
        for (int h = 0; h < 2; ++h)
#pragma unroll
            for (int p = 0; p < P_; ++p) xv[h][p] = xn[h][p];
    }

    // store partials [blk][nd][b]: lanes bl consecutive -> coalesced
    float* __restrict__ po = part + (size_t)blockIdx.x * BND_;
#pragma unroll
    for (int h = 0; h < 2; ++h)
#pragma unroll
        for (int d = 0; d < D_; ++d)
            po[(n * D_ + d) * B_ + bl + 32 * h] = acc[h][d];
}

// Parallel-wide reduce over part rows (layout [row][nd*64+b]). Block handles
// 16 k-values; 16 threads per k sum rows/16 partials with coalesced loads.
__global__ __launch_bounds__(256)
void digitcaps_reduce(const float* __restrict__ part, int rows,
                      float scale, int mode,
                      float* __restrict__ Vc, float* __restrict__ out)
{
    __shared__ float sm[4][16];
    const int t = threadIdx.x;
    const int kk = t & 15;
    const int tp = t >> 4;                // 0..15
    const int k = blockIdx.x * 16 + kk;

    float s = 0.f;
    const int steps = rows >> 4;
    const float* __restrict__ p0 = part + (size_t)tp * BND_ + k;
    const size_t stride = (size_t)16 * BND_;
#pragma unroll 8
    for (int j = 0; j < steps; ++j)
        s += p0[(size_t)j * stride];

    s += __shfl_down(s, 32);
    s += __shfl_down(s, 16);
    if ((t & 63) < 16) sm[t >> 6][kk] = s;
    __syncthreads();

    if (t < 16) {
        float tot = (sm[0][t] + sm[1][t]) + (sm[2][t] + sm[3][t]);
        tot *= scale;
        float sq = tot * tot;
        float v = tot * (sq / ((1.f + sq) * sqrtf(sq + EPS_)));
        int k2 = blockIdx.x * 16 + t;          // k2 = nd*64 + b (partial layout)
        int j = (k2 & 63) * ND_ + (k2 >> 6);   // natural [b][n][d] layout
        if (mode == 0)      Vc[j] = v;         // after iter 0: Vc = v0
        else if (mode == 1) Vc[j] += v;        // after iter 1: Vc = v0 + v1
        else                out[j] = v;        // final output [B,N,1,D]
    }
}

extern "C" void kernel_launch(void* const* d_in, const int* in_sizes, int n_in,
                              void* d_out, int out_size, void* d_ws, size_t ws_size,
                              hipStream_t stream)
{
    const float* x = (const float*)d_in[0];   // [64, 4096, 8] f32
    const float* W = (const float*)d_in[1];   // [4096, 10, 8, 16] f32
    float* out = (float*)d_out;               // [64, 10, 1, 16] f32

    // ws layout: part (512*10240 f) | Vc (10240 f) | xT (2,097,152 f) = 29.4 MB
    float* part = (float*)d_ws;
    float* Vc   = part + (size_t)ROWS_ * BND_;
    float* xT   = Vc + BND_;

    dim3 pblk(320), pgrid(ROWS_), rblk(256), rgrid(BND_ / 16);

    xT_kernel<<<dim3((B_ * I_ * P_) / 256), dim3(256), 0, stream>>>(x, xT);

    for (int pass = 0; pass < 3; ++pass) {
        if (pass == 0)
            digitcaps_pass<0><<<pgrid, pblk, 0, stream>>>(xT, W, nullptr, part);
        else
            digitcaps_pass<1><<<pgrid, pblk, 0, stream>>>(xT, W, Vc, part);
        digitcaps_reduce<<<rgrid, rblk, 0, stream>>>(part, ROWS_,
                                                     pass == 0 ? 0.1f : 1.0f, pass, Vc, out);
    }
}

// Round 12
// 171.459 us; speedup vs baseline: 1.6176x; 1.0628x over previous
//
#include <hip/hip_runtime.h>
#include <math.h>

#define B_ 64
#define I_ 4096
#define P_ 8      // Din
#define N_ 10
#define D_ 16
#define ND_ 160   // N*D
#define BND_ (B_*ND_)   // 10240
#define EPS_ 1e-7f

#define IPB_ 8                 // i per block
#define NBLK_ (I_ / IPB_)      // 512 blocks = 2 blocks/CU
#define WTILE_ (N_ * P_ * D_)  // 1280 floats of W per i

// DPP cross-lane value fetch on the VALU pipe (quad_perm, no DS traffic).
// 0xB1 = [1,0,3,2] (xor lane 1), 0x4E = [2,3,0,1] (xor lane 2).
template<int CTRL>
__device__ __forceinline__ float dpp_bcast(float v) {
    int r = __builtin_amdgcn_update_dpp(0, __float_as_int(v), CTRL, 0xF, 0xF, true);
    return __int_as_float(r);
}

// Round-12: BARRIER-FREE inner loop (theory: R8/R10's ~40 us/pass plateau is
// the per-il __syncthreads convoy — every barrier drains vmcnt/lgkmcnt for all
// 10 waves/CU in lockstep, so no wave hides another's latency).
//  - lane = bl(4b) | np(1b) | dh(1b): thread owns b = wv*16+bl, the 5 n's of
//    parity np (n = np+2k), and d-half dh (8 d). tv/acc/vc = 40 regs each.
//  - softmax entirely intra-quad: d-dot completed by 1 xor1 DPP per n (5),
//    max & expsum across n-parities by 1 xor2 DPP each (2) -> 7 DPP/thread-il
//    (R6 needed 160; R10 needed an LDS table + barrier). Waves independent.
//  - W staged in LDS once (single barrier). Reads: 80 ds_read_b128/thread-il;
//    quad addresses differ in dh (+32 B -> different banks) and np (+512 B ->
//    same banks, 2-way = free per m136).
//  - x read direct from global (xT kernel dropped): quad lanes share one 32 B
//    address; prefetched one il ahead with NO barrier to force the drain.
// __launch_bounds__(256, 2) — R2-proven; do NOT tighten (R3: cap-64 spill).
// NO cooperative launch (R11: grid.sync deadlocked the harness).
template<int MODE>
__global__ __launch_bounds__(256, 2)
void digitcaps_pass(const float* __restrict__ x, const float* __restrict__ W,
                    const float* __restrict__ Vc, float* __restrict__ part)
{
    __shared__ float wsh[IPB_ * WTILE_];   // 40960 B
    const int t = threadIdx.x;
    const int lane = t & 63;
    const int dh = lane & 1;               // d-half (0: d0..7, 1: d8..15)
    const int np = (lane >> 1) & 1;        // n-parity (owns n = np+2k)
    const int bl = lane >> 2;              // 0..15
    const int wv = t >> 6;                 // 0..3
    const int b  = wv * 16 + bl;
    const int i0 = blockIdx.x * IPB_;

    // ---- stage W[i0..i0+8) into LDS: 2560 float4, 10/thread, coalesced ----
    {
        const float4* __restrict__ Wg = (const float4*)(W + (size_t)i0 * WTILE_);
        float4* __restrict__ Ws = (float4*)wsh;
#pragma unroll
        for (int c = 0; c < (IPB_ * WTILE_) / (4 * 256); ++c)   // 10
            Ws[c * 256 + t] = Wg[c * 256 + t];
    }

    float vc[5][8];
    if (MODE == 1) {
#pragma unroll
        for (int k = 0; k < 5; ++k) {
            const float4* vp = (const float4*)(Vc + (size_t)b * ND_ + (np + 2 * k) * D_ + dh * 8);
            float4 v0 = vp[0], v1 = vp[1];
            vc[k][0]=v0.x; vc[k][1]=v0.y; vc[k][2]=v0.z; vc[k][3]=v0.w;
            vc[k][4]=v1.x; vc[k][5]=v1.y; vc[k][6]=v1.z; vc[k][7]=v1.w;
        }
    }

    float acc[5][8];
#pragma unroll
    for (int k = 0; k < 5; ++k)
#pragma unroll
        for (int d = 0; d < 8; ++d) acc[k][d] = 0.f;

    // preload x for il=0 (quad shares one 32 B address)
    float xv[P_];
    {
        const float4* xp = (const float4*)(x + ((size_t)b * I_ + i0) * P_);
        float4 a0 = xp[0], a1 = xp[1];
        xv[0]=a0.x; xv[1]=a0.y; xv[2]=a0.z; xv[3]=a0.w;
        xv[4]=a1.x; xv[5]=a1.y; xv[6]=a1.z; xv[7]=a1.w;
    }

    __syncthreads();   // ONLY barrier in the kernel (W staged)

#pragma unroll 1
    for (int il = 0; il < IPB_; ++il) {
        const float* __restrict__ Wt = wsh + il * WTILE_ + dh * 8;

        // u_hat fragments: tv[k][d] for n = np+2k, d = dh*8+d
        float tv[5][8];
#pragma unroll
        for (int k = 0; k < 5; ++k) {
            const float* __restrict__ Wn = Wt + (np + 2 * k) * (P_ * D_);
#pragma unroll
            for (int d = 0; d < 8; ++d) tv[k][d] = 0.f;
#pragma unroll
            for (int p = 0; p < P_; ++p) {
                const float4* __restrict__ wp = (const float4*)(Wn + p * D_);
                float4 wa = wp[0], wb = wp[1];
                float xp = xv[p];
                tv[k][0] = fmaf(wa.x, xp, tv[k][0]);
                tv[k][1] = fmaf(wa.y, xp, tv[k][1]);
                tv[k][2] = fmaf(wa.z, xp, tv[k][2]);
                tv[k][3] = fmaf(wa.w, xp, tv[k][3]);
                tv[k][4] = fmaf(wb.x, xp, tv[k][4]);
                tv[k][5] = fmaf(wb.y, xp, tv[k][5]);
                tv[k][6] = fmaf(wb.z, xp, tv[k][6]);
                tv[k][7] = fmaf(wb.w, xp, tv[k][7]);
            }
        }

        // prefetch x for il+1 (no barrier anywhere to force its drain)
        float xn[P_];
        if (il + 1 < IPB_) {
            const float4* xp = (const float4*)(x + ((size_t)b * I_ + i0 + il + 1) * P_);
            float4 a0 = xp[0], a1 = xp[1];
            xn[0]=a0.x; xn[1]=a0.y; xn[2]=a0.z; xn[3]=a0.w;
            xn[4]=a1.x; xn[5]=a1.y; xn[6]=a1.z; xn[7]=a1.w;
        }

        if (MODE == 0) {
            // uniform c (softmax of zeros) -> 0.1 scale applied in reduce
#pragma unroll
            for (int k = 0; k < 5; ++k)
#pragma unroll
                for (int d = 0; d < 8; ++d) acc[k][d] += tv[k][d];
        } else {
            // logits: partial d-dot, completed by xor1 (dh partner)
            float e[5];
            float m = -1e30f;
#pragma unroll
            for (int k = 0; k < 5; ++k) {
                float l = 0.f;
#pragma unroll
                for (int d = 0; d < 8; ++d) l = fmaf(tv[k][d], vc[k][d], l);
                l += dpp_bcast<0xB1>(l);          // + other d-half -> full logit
                e[k] = l;
                m = fmaxf(m, l);
            }
            m = fmaxf(m, dpp_bcast<0x4E>(m));     // max over other n-parity
            float se = 0.f;
#pragma unroll
            for (int k = 0; k < 5; ++k) { e[k] = __expf(e[k] - m); se += e[k]; }
            se += dpp_bcast<0x4E>(se);            // + other parity's expsum
            float inv = 1.f / se;
#pragma unroll
            for (int k = 0; k < 5; ++k) {
                float cn = e[k] * inv;
#pragma unroll
                for (int d = 0; d < 8; ++d)
                    acc[k][d] = fmaf(cn, tv[k][d], acc[k][d]);
            }
        }

        if (il + 1 < IPB_) {
#pragma unroll
            for (int p = 0; p < P_; ++p) xv[p] = xn[p];
        }
    }

    // store partials in NATURAL layout part[blk][b][n][d]; 10 float4/thread
    float* __restrict__ po = part + (size_t)blockIdx.x * BND_ + (size_t)b * ND_;
#pragma unroll
    for (int k = 0; k < 5; ++k) {
        float* dst = po + (np + 2 * k) * D_ + dh * 8;
        float4 s0 = {acc[k][0], acc[k][1], acc[k][2], acc[k][3]};
        float4 s1 = {acc[k][4], acc[k][5], acc[k][6], acc[k][7]};
        *(float4*)(dst)     = s0;
        *(float4*)(dst + 4) = s1;
    }
}

// Parallel-wide reduce over part rows (natural layout [row][b*160+nd]).
// Block handles 16 outputs; 16 tp-threads per output sum 32 rows each with
// coalesced loads; shfl+LDS tree.
__global__ __launch_bounds__(256)
void digitcaps_reduce(const float* __restrict__ part, float scale, int mode,
                      float* __restrict__ Vc, float* __restrict__ out)
{
    __shared__ float sm[4][16];
    const int t = threadIdx.x;
    const int kk = t & 15;
    const int tp = t >> 4;                 // 0..15
    const int k = blockIdx.x * 16 + kk;    // natural [b][n][d] index

    float s = 0.f;
    const float* __restrict__ p0 = part + (size_t)tp * BND_ + k;
#pragma unroll 8
    for (int j = 0; j < NBLK_ / 16; ++j)   // 32 rows per tp-thread
        s += p0[(size_t)j * 16 * BND_];

    s += __shfl_down(s, 32);
    s += __shfl_down(s, 16);
    if ((t & 63) < 16) sm[t >> 6][kk] = s;
    __syncthreads();

    if (t < 16) {
        float tot = (sm[0][t] + sm[1][t]) + (sm[2][t] + sm[3][t]);
        tot *= scale;
        float sq = tot * tot;
        float v = tot * (sq / ((1.f + sq) * sqrtf(sq + EPS_)));
        int j = blockIdx.x * 16 + t;       // natural layout: output index = k
        if (mode == 0)      Vc[j] = v;     // after iter 0: Vc = v0
        else if (mode == 1) Vc[j] += v;    // after iter 1: Vc = v0 + v1
        else                out[j] = v;    // final output [B,N,1,D]
    }
}

extern "C" void kernel_launch(void* const* d_in, const int* in_sizes, int n_in,
                              void* d_out, int out_size, void* d_ws, size_t ws_size,
                              hipStream_t stream)
{
    const float* x = (const float*)d_in[0];   // [64, 4096, 8] f32
    const float* W = (const float*)d_in[1];   // [4096, 10, 8, 16] f32
    float* out = (float*)d_out;               // [64, 10, 1, 16] f32

    // ws: part (512*10240 f = 21 MB) | Vc (10240 f)
    float* part = (float*)d_ws;
    float* Vc   = part + (size_t)NBLK_ * BND_;

    dim3 pblk(256), pgrid(NBLK_), rblk(256), rgrid(BND_ / 16);

    for (int pass = 0; pass < 3; ++pass) {
        if (pass == 0)
            digitcaps_pass<0><<<pgrid, pblk, 0, stream>>>(x, W, nullptr, part);
        else
            digitcaps_pass<1><<<pgrid, pblk, 0, stream>>>(x, W, Vc, part);
        digitcaps_reduce<<<rgrid, rblk, 0, stream>>>(part, pass == 0 ? 0.1f : 1.0f,
                                                     pass, Vc, out);
    }
}